// Round 5
// baseline (40.690 us; speedup 1.0000x reference)
//
#include <hip/hip_runtime.h>
#include <math.h>

namespace {

constexpr int BB = 8;
constexpr int NN = 1024;
constexpr int CC = 10;
constexpr float RADIUS = 0.04f;
constexpr float ACCEL_SCALE = 0.02f;
constexpr float MAX_VEL = 0.02f;
constexpr float MAX_POS = 1.0f;
constexpr float EPS = 1e-9f;
// prefilter threshold: R^2 = 0.0016; margin covers fma-contraction + EPS + ulps
constexpr float D2_PREFILTER = 0.0017f;

// ONE kernel, no workspace. grid = 1024 blocks (8 batches x 128 chunks),
// block = 256 threads. 8 i-rows per block, 32 subs per row, 32 j's per sub.
// Full batch state lives transposed in LDS (xs[c][j]) so the common-path
// pair test is 2 conflict-free ds_reads and the rare hit-branch MLP has
// zero global-memory latency.
__global__ __launch_bounds__(256) void gnca_fused(
    const float* __restrict__ x,   // (B, N, 10)
    const float* __restrict__ W1,  // (14, 16) row-major
    const float* __restrict__ b1,  // (16,)
    const float* __restrict__ W2,  // (16, 7) row-major
    const float* __restrict__ b2,  // (7,)
    float* __restrict__ out)       // (B, N, 10)
{
    __shared__ float xs[CC][NN];    // 40 KB, transposed state
    __shared__ float W1b_s[240];    // W1 (224) then b1 (16)
    __shared__ float W2c_s[32];     // W2 col 0 (16), col 1 (16)

    const int tid = threadIdx.x;
    const int blk = blockIdx.x;          // 0..1023
    const int b = blk >> 7;              // batch
    const int i_base = (blk & 127) * 8;  // 8 i-rows per block

    if (tid < 224) W1b_s[tid] = W1[tid];
    else if (tid < 240) W1b_s[tid] = b1[tid - 224];
    if (tid < 32) W2c_s[tid] = W2[(tid & 15) * 7 + (tid >> 4)];

    const float* __restrict__ xb = x + (size_t)b * NN * CC;

    // stage transposed: xs[c][j] = x[b,j,c]; ds_writes are lane-consecutive in j
    for (int j = tid; j < NN; j += 256) {
        const float* __restrict__ xr = xb + j * CC;
        float r[CC];
#pragma unroll
        for (int c = 0; c < CC; ++c) r[c] = xr[c];
#pragma unroll
        for (int c = 0; c < CC; ++c) xs[c][j] = r[c];
    }
    __syncthreads();

    const int i_local = tid >> 5;   // 0..7
    const int sub     = tid & 31;   // 0..31
    const int i = i_base + i_local;

    const float pix = xs[0][i];
    const float piy = xs[1][i];

    float o0p = 0.0f, o1p = 0.0f, deg = 0.0f, cellnb = 0.0f;

    for (int jj = 0; jj < NN / 32; ++jj) {
        const int j = jj * 32 + sub;
        const float dx = xs[0][j] - pix;   // rel = pos[j] - pos[i]
        const float dy = xs[1][j] - piy;
        const float d2c = dx * dx + dy * dy;   // contraction ok: prefilter only
        if (d2c < D2_PREFILTER) {
            // exact fp32 path, matches numpy boundary decisions bit-for-bit
            const float d2 = __fadd_rn(__fadd_rn(__fmul_rn(dx, dx), __fmul_rn(dy, dy)), EPS);
            const float dist = __fsqrt_rn(d2);
            if (dist < RADIUS && dist > 1e-6f) {
                const float tgt = xs[4][j];
                deg += 1.0f;
                cellnb += (tgt > 0.5f) ? 1.0f : 0.0f;
                float xv[CC];
#pragma unroll
                for (int c = 0; c < CC; ++c) xv[c] = xs[c][j];
#pragma unroll
                for (int h = 0; h < 16; ++h) {
                    float v = W1b_s[224 + h] + dist * W1b_s[h] + dx * W1b_s[16 + h]
                            + dy * W1b_s[32 + h] + tgt * W1b_s[48 + h];
#pragma unroll
                    for (int c = 0; c < CC; ++c) v = fmaf(xv[c], W1b_s[(4 + c) * 16 + h], v);
                    v = fmaxf(v, 0.0f);
                    // fold the two needed W2 columns immediately: no agg[16]
                    o0p = fmaf(v, W2c_s[h], o0p);
                    o1p = fmaf(v, W2c_s[16 + h], o1p);
                }
            }
        }
    }

    // reduce over 32 subs (aligned 32-lane groups; xor masks < 32 stay in-group)
#pragma unroll
    for (int m = 1; m < 32; m <<= 1) {
        o0p    += __shfl_xor(o0p, m, 64);
        o1p    += __shfl_xor(o1p, m, 64);
        deg    += __shfl_xor(deg, m, 64);
        cellnb += __shfl_xor(cellnb, m, 64);
    }

    if (sub == 0) {
        const bool is_cell = xs[4][i] > 0.5f;

        float o0 = deg * b2[0] + o0p;
        float o1 = deg * b2[1] + o1p;
        if (!is_cell) { o0 = 0.0f; o1 = 0.0f; }

        const float vx = xs[2][i];
        const float vy = xs[3][i];
        float nvx = vx, nvy = vy;
        float npx = pix, npy = piy;
        if (is_cell) {
            nvx = fminf(fmaxf(vx + o0 * ACCEL_SCALE, -MAX_VEL), MAX_VEL);
            nvy = fminf(fmaxf(vy + o1 * ACCEL_SCALE, -MAX_VEL), MAX_VEL);
            npx = fminf(fmaxf(pix + nvx, -MAX_POS), MAX_POS);
            npy = fminf(fmaxf(piy + nvy, -MAX_POS), MAX_POS);
        }

        const bool dead     = is_cell && (deg < 3.0f);
        const bool consumed = (!is_cell) && (cellnb >= 1.0f);
        const float keep = (dead || consumed) ? 0.0f : 1.0f;

        float* __restrict__ op = out + ((size_t)b * NN + i) * CC;
        op[0] = npx * keep;
        op[1] = npy * keep;
        op[2] = nvx * keep;
        op[3] = nvy * keep;
#pragma unroll
        for (int c = 4; c < CC; ++c) op[c] = xs[c][i] * keep;
    }
}

}  // namespace

extern "C" void kernel_launch(void* const* d_in, const int* in_sizes, int n_in,
                              void* d_out, int out_size, void* d_ws, size_t ws_size,
                              hipStream_t stream) {
    const float* x  = (const float*)d_in[0];
    const float* W1 = (const float*)d_in[1];
    const float* b1 = (const float*)d_in[2];
    const float* W2 = (const float*)d_in[3];
    const float* b2 = (const float*)d_in[4];
    float* out = (float*)d_out;

    gnca_fused<<<dim3(BB * 128), dim3(256), 0, stream>>>(x, W1, b1, W2, b2, out);
}

// Round 6
// 20.590 us; speedup vs baseline: 1.9762x; 1.9762x over previous
//
#include <hip/hip_runtime.h>
#include <math.h>

namespace {

constexpr int BB = 8;
constexpr int NN = 1024;
constexpr int CC = 10;
constexpr float RADIUS = 0.04f;
constexpr float ACCEL_SCALE = 0.02f;
constexpr float MAX_VEL = 0.02f;
constexpr float MAX_POS = 1.0f;
constexpr float EPS = 1e-9f;
// prefilter threshold: R^2 = 0.0016; margin covers fma-contraction + EPS + ulps
constexpr float D2_PREFILTER = 0.0017f;

// ONE kernel. grid = 512 blocks (8 batches x 64 chunks of 16 rows),
// block = 512 threads = 8 waves; wave w handles rows {2w, 2w+1}, 64 subs/row,
// 16 j's per sub (fully unrolled -> batched LDS reads).
// State+feat live in LDS (S[19][1024], 76 KB -> 2 blocks/CU = 4 waves/SIMD).
// ALL weights are read from global with compile-time offsets: uniform address
// -> s_load + v_fma(v,s,v); zero LDS traffic, zero VGPR cost for weights.
__global__ __launch_bounds__(512) void gnca_one(
    const float* __restrict__ x,   // (B, N, 10)
    const float* __restrict__ W1,  // (14, 16) row-major
    const float* __restrict__ b1,  // (16,)
    const float* __restrict__ W2,  // (16, 7) row-major
    const float* __restrict__ b2,  // (7,)
    float* __restrict__ out)       // (B, N, 10)
{
    // rows: 0 = pos.x, 1 = pos.y, 2 = typ, 3+h = feat[h] = b1[h] + x.W1x
    __shared__ float S[19][NN];    // 76 KB

    const int tid = threadIdx.x;
    const int blk = blockIdx.x;          // 0..511
    const int b = blk >> 6;              // batch
    const int row0 = (blk & 63) * 16;    // 16 i-rows per block

    const float* __restrict__ xb = x + (size_t)b * NN * CC;

    // ---- stage state + per-node features (each thread: 2 nodes) ----
    for (int j = tid; j < NN; j += 512) {
        const float* __restrict__ xr = xb + j * CC;
        float xv[CC];
#pragma unroll
        for (int c = 0; c < CC; ++c) xv[c] = xr[c];
        S[0][j] = xv[0];
        S[1][j] = xv[1];
        S[2][j] = xv[4];
#pragma unroll
        for (int h = 0; h < 16; ++h) {
            float a = b1[h];               // uniform -> s_load
#pragma unroll
            for (int c = 0; c < CC; ++c)
                a = fmaf(xv[c], W1[(4 + c) * 16 + h], a);   // v_fma v,s,v
            S[3 + h][j] = a;
        }
    }
    __syncthreads();

    const int w   = tid >> 6;   // wave 0..7
    const int sub = tid & 63;   // 0..63

#pragma unroll
    for (int r = 0; r < 2; ++r) {
        const int i = row0 + w * 2 + r;
        const float pix = S[0][i];          // uniform in wave -> broadcast
        const float piy = S[1][i];

        float o0p = 0.0f, o1p = 0.0f, deg = 0.0f, cn = 0.0f;

#pragma unroll
        for (int jj = 0; jj < 16; ++jj) {
            const int j = jj * 64 + sub;
            const float dx = S[0][j] - pix;   // rel = pos[j] - pos[i]
            const float dy = S[1][j] - piy;
            const float d2c = dx * dx + dy * dy;   // contraction ok: prefilter
            if (d2c < D2_PREFILTER) {
                // exact fp32 path: matches numpy boundary decisions bit-for-bit
                const float d2 =
                    __fadd_rn(__fadd_rn(__fmul_rn(dx, dx), __fmul_rn(dy, dy)), EPS);
                const float dist = __fsqrt_rn(d2);
                if (dist < RADIUS && dist > 1e-6f) {
                    const float tgt = S[2][j];
                    deg += 1.0f;
                    cn += (tgt > 0.5f) ? 1.0f : 0.0f;
#pragma unroll
                    for (int h = 0; h < 16; ++h) {
                        float v = S[3 + h][j];
                        v = fmaf(tgt,  W1[48 + h], v);   // uniform weights ->
                        v = fmaf(dy,   W1[32 + h], v);   // s_load + v_fma(v,s,v)
                        v = fmaf(dx,   W1[16 + h], v);
                        v = fmaf(dist, W1[h],      v);
                        v = fmaxf(v, 0.0f);
                        o0p = fmaf(v, W2[h * 7 + 0], o0p);
                        o1p = fmaf(v, W2[h * 7 + 1], o1p);
                    }
                }
            }
        }

        // butterfly reduce over the 64 subs
#pragma unroll
        for (int m = 1; m < 64; m <<= 1) {
            o0p += __shfl_xor(o0p, m, 64);
            o1p += __shfl_xor(o1p, m, 64);
            deg += __shfl_xor(deg, m, 64);
            cn  += __shfl_xor(cn,  m, 64);
        }

        if (sub == 0) {
            const bool is_cell = S[2][i] > 0.5f;

            float o0 = deg * b2[0] + o0p;
            float o1 = deg * b2[1] + o1p;
            if (!is_cell) { o0 = 0.0f; o1 = 0.0f; }

            const float* __restrict__ xr = xb + i * CC;
            const float vx = xr[2];
            const float vy = xr[3];
            float nvx = vx, nvy = vy;
            float npx = pix, npy = piy;
            if (is_cell) {
                nvx = fminf(fmaxf(vx + o0 * ACCEL_SCALE, -MAX_VEL), MAX_VEL);
                nvy = fminf(fmaxf(vy + o1 * ACCEL_SCALE, -MAX_VEL), MAX_VEL);
                npx = fminf(fmaxf(pix + nvx, -MAX_POS), MAX_POS);
                npy = fminf(fmaxf(piy + nvy, -MAX_POS), MAX_POS);
            }

            const bool dead     = is_cell && (deg < 3.0f);
            const bool consumed = (!is_cell) && (cn >= 1.0f);
            const float keep = (dead || consumed) ? 0.0f : 1.0f;

            float* __restrict__ op = out + ((size_t)b * NN + i) * CC;
            op[0] = npx * keep;
            op[1] = npy * keep;
            op[2] = nvx * keep;
            op[3] = nvy * keep;
            op[4] = S[2][i] * keep;
#pragma unroll
            for (int c = 5; c < CC; ++c) op[c] = xr[c] * keep;
        }
    }
}

}  // namespace

extern "C" void kernel_launch(void* const* d_in, const int* in_sizes, int n_in,
                              void* d_out, int out_size, void* d_ws, size_t ws_size,
                              hipStream_t stream) {
    const float* x  = (const float*)d_in[0];
    const float* W1 = (const float*)d_in[1];
    const float* b1 = (const float*)d_in[2];
    const float* W2 = (const float*)d_in[3];
    const float* b2 = (const float*)d_in[4];
    float* out = (float*)d_out;

    gnca_one<<<dim3(512), dim3(512), 0, stream>>>(x, W1, b1, W2, b2, out);
}

// Round 7
// 18.598 us; speedup vs baseline: 2.1879x; 1.1071x over previous
//
#include <hip/hip_runtime.h>
#include <math.h>

namespace {

constexpr int BB = 8;
constexpr int NN = 1024;
constexpr int CC = 10;
constexpr float RADIUS = 0.04f;
constexpr float ACCEL_SCALE = 0.02f;
constexpr float MAX_VEL = 0.02f;
constexpr float MAX_POS = 1.0f;
constexpr float EPS = 1e-9f;
// prefilter threshold: R^2 = 0.0016; margin covers fma-contraction + EPS + ulps
constexpr float D2_PREFILTER = 0.0017f;

// ONE kernel. grid = 512 blocks (8 batches x 64 chunks of 16 rows),
// block = 512 threads = 8 waves; wave w handles rows {2w, 2w+1}, 64 subs/row.
// Staging is fully coalesced: float4 global loads -> LDS raw -> per-node
// gather via ds_read_b128 (the LDS roundtrip IS the transpose).
// Weights stay in global with compile-time offsets -> s_load + v_fma(v,s,v).
__global__ __launch_bounds__(512) void gnca_one(
    const float* __restrict__ x,   // (B, N, 10)
    const float* __restrict__ W1,  // (14, 16) row-major
    const float* __restrict__ b1,  // (16,)
    const float* __restrict__ W2,  // (16, 7) row-major
    const float* __restrict__ b2,  // (7,)
    float* __restrict__ out)       // (B, N, 10)
{
    __shared__ float2 pos2[NN];     // 8 KB
    __shared__ float  typs[NN];     // 4 KB
    __shared__ float  F[16][NN];    // 64 KB; F[0..9] doubles as raw x staging

    const int tid = threadIdx.x;
    const int blk = blockIdx.x;          // 0..511
    const int b = blk >> 6;              // batch
    const int row0 = (blk & 63) * 16;    // 16 i-rows per block

    const float* __restrict__ xb = x + (size_t)b * NN * CC;

    // ---- Phase A: coalesced copy of x[b] (40 KB) into LDS raw region ----
    {
        const float4* __restrict__ src = (const float4*)xb;   // 2560 float4
        float4* __restrict__ dst = (float4*)&F[0][0];
        const float4 s0 = src[tid];
        const float4 s1 = src[512 + tid];
        const float4 s2 = src[1024 + tid];
        const float4 s3 = src[1536 + tid];
        const float4 s4 = src[2048 + tid];
        dst[tid] = s0;
        dst[512 + tid] = s1;
        dst[1024 + tid] = s2;
        dst[1536 + tid] = s3;
        dst[2048 + tid] = s4;
    }
    __syncthreads();

    // ---- Phase B: gather my two nodes (2t, 2t+1) = float4[5t .. 5t+4] ----
    float xv0[CC], xv1[CC];
    {
        const float4* __restrict__ raw4 = (const float4*)&F[0][0];
        const float4 r0 = raw4[tid * 5 + 0];   // 16B-aligned, 2-way alias (free)
        const float4 r1 = raw4[tid * 5 + 1];
        const float4 r2 = raw4[tid * 5 + 2];
        const float4 r3 = raw4[tid * 5 + 3];
        const float4 r4 = raw4[tid * 5 + 4];
        xv0[0]=r0.x; xv0[1]=r0.y; xv0[2]=r0.z; xv0[3]=r0.w;
        xv0[4]=r1.x; xv0[5]=r1.y; xv0[6]=r1.z; xv0[7]=r1.w;
        xv0[8]=r2.x; xv0[9]=r2.y;
        xv1[0]=r2.z; xv1[1]=r2.w;
        xv1[2]=r3.x; xv1[3]=r3.y; xv1[4]=r3.z; xv1[5]=r3.w;
        xv1[6]=r4.x; xv1[7]=r4.y; xv1[8]=r4.z; xv1[9]=r4.w;
    }
    const int j0 = tid * 2, j1 = tid * 2 + 1;
    pos2[j0] = make_float2(xv0[0], xv0[1]);
    pos2[j1] = make_float2(xv1[0], xv1[1]);
    typs[j0] = xv0[4];
    typs[j1] = xv1[4];
    __syncthreads();   // all raw reads done before F is overwritten

    // ---- Phase C: per-node features into F (overwrites raw region) ----
#pragma unroll
    for (int h = 0; h < 16; ++h) {
        float a0 = b1[h];                      // uniform -> s_load
        float a1 = a0;
#pragma unroll
        for (int c = 0; c < CC; ++c) {
            const float wv = W1[(4 + c) * 16 + h];   // uniform -> s_load
            a0 = fmaf(xv0[c], wv, a0);
            a1 = fmaf(xv1[c], wv, a1);
        }
        *(float2*)&F[h][j0] = make_float2(a0, a1);   // b64, 2-way alias (free)
    }
    __syncthreads();

    // ---- sweep ----
    const int w   = tid >> 6;   // wave 0..7
    const int sub = tid & 63;   // 0..63

#pragma unroll
    for (int r = 0; r < 2; ++r) {
        const int i = row0 + w * 2 + r;
        const float2 pi = pos2[i];          // wave-uniform -> broadcast

        float o0p = 0.0f, o1p = 0.0f, deg = 0.0f, cn = 0.0f;

#pragma unroll
        for (int jj = 0; jj < 16; ++jj) {
            const int j = jj * 64 + sub;
            const float2 pj = pos2[j];      // one ds_read_b64, conflict-free
            const float dx = pj.x - pi.x;   // rel = pos[j] - pos[i]
            const float dy = pj.y - pi.y;
            const float d2c = dx * dx + dy * dy;   // contraction ok: prefilter
            if (d2c < D2_PREFILTER) {
                // exact fp32 path: matches numpy boundary decisions bit-for-bit
                const float d2 =
                    __fadd_rn(__fadd_rn(__fmul_rn(dx, dx), __fmul_rn(dy, dy)), EPS);
                const float dist = __fsqrt_rn(d2);
                if (dist < RADIUS && dist > 1e-6f) {
                    const float tgt = typs[j];
                    deg += 1.0f;
                    cn += (tgt > 0.5f) ? 1.0f : 0.0f;
#pragma unroll
                    for (int h = 0; h < 16; ++h) {
                        float v = F[h][j];
                        v = fmaf(tgt,  W1[48 + h], v);   // uniform weights ->
                        v = fmaf(dy,   W1[32 + h], v);   // s_load + v_fma(v,s,v)
                        v = fmaf(dx,   W1[16 + h], v);
                        v = fmaf(dist, W1[h],      v);
                        v = fmaxf(v, 0.0f);
                        o0p = fmaf(v, W2[h * 7 + 0], o0p);
                        o1p = fmaf(v, W2[h * 7 + 1], o1p);
                    }
                }
            }
        }

        // butterfly reduce over the 64 subs
#pragma unroll
        for (int m = 1; m < 64; m <<= 1) {
            o0p += __shfl_xor(o0p, m, 64);
            o1p += __shfl_xor(o1p, m, 64);
            deg += __shfl_xor(deg, m, 64);
            cn  += __shfl_xor(cn,  m, 64);
        }

        if (sub == 0) {
            const float typ_i = typs[i];
            const bool is_cell = typ_i > 0.5f;

            float o0 = deg * b2[0] + o0p;
            float o1 = deg * b2[1] + o1p;
            if (!is_cell) { o0 = 0.0f; o1 = 0.0f; }

            const float* __restrict__ xr = xb + i * CC;
            const float vx = xr[2];
            const float vy = xr[3];
            float nvx = vx, nvy = vy;
            float npx = pi.x, npy = pi.y;
            if (is_cell) {
                nvx = fminf(fmaxf(vx + o0 * ACCEL_SCALE, -MAX_VEL), MAX_VEL);
                nvy = fminf(fmaxf(vy + o1 * ACCEL_SCALE, -MAX_VEL), MAX_VEL);
                npx = fminf(fmaxf(pi.x + nvx, -MAX_POS), MAX_POS);
                npy = fminf(fmaxf(pi.y + nvy, -MAX_POS), MAX_POS);
            }

            const bool dead     = is_cell && (deg < 3.0f);
            const bool consumed = (!is_cell) && (cn >= 1.0f);
            const float keep = (dead || consumed) ? 0.0f : 1.0f;

            float* __restrict__ op = out + ((size_t)b * NN + i) * CC;
            op[0] = npx * keep;
            op[1] = npy * keep;
            op[2] = nvx * keep;
            op[3] = nvy * keep;
            op[4] = typ_i * keep;
#pragma unroll
            for (int c = 5; c < CC; ++c) op[c] = xr[c] * keep;
        }
    }
}

}  // namespace

extern "C" void kernel_launch(void* const* d_in, const int* in_sizes, int n_in,
                              void* d_out, int out_size, void* d_ws, size_t ws_size,
                              hipStream_t stream) {
    const float* x  = (const float*)d_in[0];
    const float* W1 = (const float*)d_in[1];
    const float* b1 = (const float*)d_in[2];
    const float* W2 = (const float*)d_in[3];
    const float* b2 = (const float*)d_in[4];
    float* out = (float*)d_out;

    gnca_one<<<dim3(512), dim3(512), 0, stream>>>(x, W1, b1, W2, b2, out);
}

// Round 8
// 17.192 us; speedup vs baseline: 2.3668x; 1.0818x over previous
//
#include <hip/hip_runtime.h>
#include <math.h>

namespace {

constexpr int BB = 8;
constexpr int NN = 1024;
constexpr int CC = 10;
constexpr float RADIUS = 0.04f;
constexpr float ACCEL_SCALE = 0.02f;
constexpr float MAX_VEL = 0.02f;
constexpr float MAX_POS = 1.0f;
constexpr float EPS = 1e-9f;
// superset prefilter: exact-hit requires dx^2+dy^2 < 0.00160001; margin to 0.0017
constexpr float D2_PREFILTER = 0.0017f;

// ---------------- K1: per-node features, ONCE per node ----------------
// F[g][0..15] = b1 + x[g]·W1x ; P[g] = pos ; T[g] = typ   (g = b*N+j)
__global__ __launch_bounds__(256) void k_feat(
    const float* __restrict__ x, const float* __restrict__ W1,
    const float* __restrict__ b1,
    float* __restrict__ F, float2* __restrict__ P, float* __restrict__ T)
{
    const int g = blockIdx.x * 256 + threadIdx.x;   // 0..8191
    const float2* __restrict__ xr2 = (const float2*)(x + (size_t)g * CC);
    const float2 a0 = xr2[0], a1 = xr2[1], a2 = xr2[2], a3 = xr2[3], a4 = xr2[4];
    const float xv[CC] = {a0.x, a0.y, a1.x, a1.y, a2.x,
                          a2.y, a3.x, a3.y, a4.x, a4.y};
    P[g] = make_float2(xv[0], xv[1]);
    T[g] = xv[4];

    float f[16];
#pragma unroll
    for (int h = 0; h < 16; ++h) {
        float a = b1[h];                                  // uniform -> s_load
#pragma unroll
        for (int c = 0; c < CC; ++c) a = fmaf(xv[c], W1[(4 + c) * 16 + h], a);
        f[h] = a;
    }
    float4* __restrict__ fo = (float4*)(F + (size_t)g * 16);
    fo[0] = make_float4(f[0], f[1], f[2], f[3]);
    fo[1] = make_float4(f[4], f[5], f[6], f[7]);
    fo[2] = make_float4(f[8], f[9], f[10], f[11]);
    fo[3] = make_float4(f[12], f[13], f[14], f[15]);
}

// ---------------- K2: pair sweep with ballot-compacted hits ----------------
// grid = 512 blocks (8 batches x 64 chunks of 16 rows), block = 512 = 8 waves.
// Wave w owns rows {2w, 2w+1}; 64 subs per row; 16 j's per sub.
__global__ __launch_bounds__(512) void k_sweep(
    const float* __restrict__ x,   // (B,N,10) original state (tail channels)
    const float* __restrict__ W1,  // (14,16)
    const float* __restrict__ W2,  // (16,7)
    const float* __restrict__ b2,  // (7,)
    const float* __restrict__ F,   // (B*N,16)
    const float2* __restrict__ P,  // (B*N)
    const float* __restrict__ T,   // (B*N)
    float* __restrict__ out)       // (B,N,10)
{
    __shared__ float2 pos_s[NN];      // 8 KB
    __shared__ float  typ_s[NN];      // 4 KB
    __shared__ float  F_s[NN * 16];   // 64 KB

    const int tid = threadIdx.x;
    const int blk = blockIdx.x;          // 0..511
    const int b = blk >> 6;              // batch
    const int row0 = (blk & 63) * 16;    // 16 i-rows per block

    const int w   = tid >> 6;   // wave 0..7
    const int sub = tid & 63;   // 0..63
    const int hh  = sub & 15;   // this lane's h-slice (fixed)

    // per-lane h-slice weights (6 vector loads, issued early, L2-resident)
    const float w1d = W1[hh];
    const float w1x = W1[16 + hh];
    const float w1y = W1[32 + hh];
    const float w1t = W1[48 + hh];
    const float w20 = W2[hh * 7 + 0];
    const float w21 = W2[hh * 7 + 1];

    // wave-uniform prefetch of row data (scalar loads, overlap staging)
    const int iu0 = __builtin_amdgcn_readfirstlane(row0 + w * 2);
    const int iu1 = iu0 + 1;
    const float2 pi0 = P[(size_t)b * NN + iu0];
    const float2 pi1 = P[(size_t)b * NN + iu1];
    const float* __restrict__ xr0 = x + ((size_t)b * NN + iu0) * CC;
    const float* __restrict__ xr1 = x + ((size_t)b * NN + iu1) * CC;
    const float t0v2 = xr0[2], t0v3 = xr0[3], t0c5 = xr0[5], t0c6 = xr0[6],
                t0c7 = xr0[7], t0c8 = xr0[8], t0c9 = xr0[9];
    const float t1v2 = xr1[2], t1v3 = xr1[3], t1c5 = xr1[5], t1c6 = xr1[6],
                t1c7 = xr1[7], t1c8 = xr1[8], t1c9 = xr1[9];

    // ---- coalesced staging: P (1 float4), T (0.5), F (8) per thread ----
    {
        const float4* __restrict__ ps = (const float4*)(P + (size_t)b * NN);
        ((float4*)pos_s)[tid] = ps[tid];                       // 512 float4
        if (tid < 256) {
            const float4* __restrict__ ts = (const float4*)(T + (size_t)b * NN);
            ((float4*)typ_s)[tid] = ts[tid];                   // 256 float4
        }
        const float4* __restrict__ fs = (const float4*)(F + (size_t)b * NN * 16);
        float4* __restrict__ fd = (float4*)F_s;                // 4096 float4
#pragma unroll
        for (int k = 0; k < 8; ++k) fd[k * 512 + tid] = fs[k * 512 + tid];
    }
    __syncthreads();

#pragma unroll
    for (int r = 0; r < 2; ++r) {
        const int   iu = r ? iu1 : iu0;
        const float2 pi = r ? pi1 : pi0;

        float o0p = 0.0f, o1p = 0.0f, deg = 0.0f, cn = 0.0f;

        float2 pj = pos_s[sub];                    // software pipeline stage
        for (int jj = 0; jj < 16; ++jj) {
            const float2 pjn = pos_s[(((jj + 1) & 15) << 6) + sub];  // prefetch
            const float dx = pj.x - pi.x;          // rel = pos[j] - pos[i]
            const float dy = pj.y - pi.y;
            const float d2c = dx * dx + dy * dy;   // contraction ok: prefilter
            unsigned long long m = __ballot(d2c < D2_PREFILTER);
            while (m) {
                const int src = __builtin_ctzll(m);
                m &= (m - 1);
                const float bx = __shfl(dx, src, 64);   // broadcast hit's rel
                const float by = __shfl(dy, src, 64);
                // exact fp32 path: bit-identical to numpy's boundary decisions
                const float d2 =
                    __fadd_rn(__fadd_rn(__fmul_rn(bx, bx), __fmul_rn(by, by)), EPS);
                const float dist = __fsqrt_rn(d2);
                if (dist < RADIUS) {               // uniform across wave
                    const int bj = (jj << 6) + src;
                    const float tgt = typ_s[bj];            // broadcast read
                    const float fv  = F_s[bj * 16 + hh];    // 16 banks, 4x bcast
                    float v = fmaf(tgt, w1t, fv);
                    v = fmaf(by, w1y, v);
                    v = fmaf(bx, w1x, v);
                    v = fmaf(dist, w1d, v);
                    v = fmaxf(v, 0.0f);
                    o0p = fmaf(v, w20, o0p);       // per-lane h-slice partial
                    o1p = fmaf(v, w21, o1p);
                    deg += 1.0f;                   // uniform on all lanes
                    cn  += (tgt > 0.5f) ? 1.0f : 0.0f;
                }
            }
            pj = pjn;
        }

        // reduce o0p/o1p over 64 lanes (4 h-replica groups -> x0.25 later)
#pragma unroll
        for (int mm = 1; mm < 64; mm <<= 1) {
            o0p += __shfl_xor(o0p, mm, 64);
            o1p += __shfl_xor(o1p, mm, 64);
        }

        if (sub == 0) {
            const float typ_i = typ_s[iu];
            const bool is_cell = typ_i > 0.5f;

            float o0 = deg * b2[0] + o0p * 0.25f;   // /4 replicas, exact
            float o1 = deg * b2[1] + o1p * 0.25f;
            if (!is_cell) { o0 = 0.0f; o1 = 0.0f; }

            const float vx = r ? t1v2 : t0v2;
            const float vy = r ? t1v3 : t0v3;
            float nvx = vx, nvy = vy;
            float npx = pi.x, npy = pi.y;
            if (is_cell) {
                nvx = fminf(fmaxf(vx + o0 * ACCEL_SCALE, -MAX_VEL), MAX_VEL);
                nvy = fminf(fmaxf(vy + o1 * ACCEL_SCALE, -MAX_VEL), MAX_VEL);
                npx = fminf(fmaxf(pi.x + nvx, -MAX_POS), MAX_POS);
                npy = fminf(fmaxf(pi.y + nvy, -MAX_POS), MAX_POS);
            }

            const bool dead     = is_cell && (deg < 3.0f);
            const bool consumed = (!is_cell) && (cn >= 1.0f);
            const float keep = (dead || consumed) ? 0.0f : 1.0f;

            const float c5 = r ? t1c5 : t0c5, c6 = r ? t1c6 : t0c6;
            const float c7 = r ? t1c7 : t0c7, c8 = r ? t1c8 : t0c8;
            const float c9 = r ? t1c9 : t0c9;

            float2* __restrict__ op2 = (float2*)(out + ((size_t)b * NN + iu) * CC);
            op2[0] = make_float2(npx * keep, npy * keep);
            op2[1] = make_float2(nvx * keep, nvy * keep);
            op2[2] = make_float2(typ_i * keep, c5 * keep);
            op2[3] = make_float2(c6 * keep, c7 * keep);
            op2[4] = make_float2(c8 * keep, c9 * keep);
        }
    }
}

}  // namespace

extern "C" void kernel_launch(void* const* d_in, const int* in_sizes, int n_in,
                              void* d_out, int out_size, void* d_ws, size_t ws_size,
                              hipStream_t stream) {
    const float* x  = (const float*)d_in[0];
    const float* W1 = (const float*)d_in[1];
    const float* b1 = (const float*)d_in[2];
    const float* W2 = (const float*)d_in[3];
    const float* b2 = (const float*)d_in[4];
    float* out = (float*)d_out;

    // ws layout: F fp32 (512 KB) | P float2 (64 KB) | T float (32 KB)
    float*  F = (float*)d_ws;
    float2* P = (float2*)((char*)d_ws + (size_t)BB * NN * 16 * sizeof(float));
    float*  T = (float*)((char*)P + (size_t)BB * NN * sizeof(float2));

    k_feat<<<dim3(BB * NN / 256), dim3(256), 0, stream>>>(x, W1, b1, F, P, T);
    k_sweep<<<dim3(BB * 64), dim3(512), 0, stream>>>(x, W1, W2, b2, F, P, T, out);
}

// Round 9
// 12.378 us; speedup vs baseline: 3.2872x; 1.3889x over previous
//
#include <hip/hip_runtime.h>
#include <math.h>

namespace {

constexpr int BB = 8;
constexpr int NN = 1024;
constexpr int CC = 10;
constexpr float RADIUS = 0.04f;
constexpr float ACCEL_SCALE = 0.02f;
constexpr float MAX_VEL = 0.02f;
constexpr float MAX_POS = 1.0f;
constexpr float EPS = 1e-9f;
// superset prefilter: exact hit needs d2 < 0.0016; margin covers fma + ulps
constexpr float D2_PREFILTER = 0.0017f;

// ONE kernel, no workspace. grid = 512 blocks (8 batches x 64 chunks of 16
// rows), block = 512 threads = 8 waves. Wave w owns rows {2w, 2w+1}; both
// rows share each pos2[j] read (2 ballots/iter). Hits are ballot-compacted;
// the hit body recomputes feat on the fly: 5 broadcast ds_read_b64 of the
// raw x row + 14 FMA with per-lane h-slice weights (lane h = sub & 15,
// 4 replicas -> exact x0.25 fold after the butterfly reduce).
__global__ __launch_bounds__(512, 4) void gnca_one(
    const float* __restrict__ x,   // (B, N, 10)
    const float* __restrict__ W1,  // (14, 16) row-major
    const float* __restrict__ b1,  // (16,)
    const float* __restrict__ W2,  // (16, 7) row-major
    const float* __restrict__ b2,  // (7,)
    float* __restrict__ out)       // (B, N, 10)
{
    __shared__ alignas(16) float2 raw2[NN * 5];   // 40 KB: x[b] row-major
    __shared__ alignas(16) float2 pos2[NN];       // 8 KB

    const int tid = threadIdx.x;
    const int blk = blockIdx.x;          // 0..511
    const int b = blk >> 6;              // batch
    const int row0 = (blk & 63) * 16;    // 16 i-rows per block
    const int w   = tid >> 6;            // wave 0..7
    const int sub = tid & 63;            // 0..63
    const int hh  = sub & 15;            // this lane's h-slice

    // per-lane h-slice weights (vector loads, issued early, L2-resident)
    const float b1h = b1[hh];
    const float w1d = W1[hh];
    const float w1x = W1[16 + hh];
    const float w1y = W1[32 + hh];
    const float w1t = W1[48 + hh];
    float w1c[CC];
#pragma unroll
    for (int c = 0; c < CC; ++c) w1c[c] = W1[(4 + c) * 16 + hh];
    const float w20 = W2[hh * 7 + 0];
    const float w21 = W2[hh * 7 + 1];

    const float* __restrict__ xb = x + (size_t)b * NN * CC;

    // ---- Phase A: coalesced copy of x[b] (40 KB) into LDS ----
    {
        const float4* __restrict__ src = (const float4*)xb;   // 2560 float4
        float4* __restrict__ dst = (float4*)raw2;
#pragma unroll
        for (int k = 0; k < 5; ++k) dst[k * 512 + tid] = src[k * 512 + tid];
    }
    __syncthreads();

    // ---- Phase B: extract pos2 (thread t -> nodes 2t, 2t+1) ----
    {
        const float4* __restrict__ r4 = (const float4*)raw2;
        const float4 r0 = r4[tid * 5 + 0];   // node 2t   ch 0..3
        const float4 r2 = r4[tid * 5 + 2];   // node 2t+1 ch 0,1 in .z,.w
        ((float4*)pos2)[tid] = make_float4(r0.x, r0.y, r2.z, r2.w);
    }
    __syncthreads();

    const int iu0 = row0 + w * 2;
    const int iu1 = iu0 + 1;
    const float2 pi0 = pos2[iu0];   // wave-uniform -> broadcast
    const float2 pi1 = pos2[iu1];

    float o0p_r0 = 0.0f, o1p_r0 = 0.0f, dg0 = 0.0f, cn0 = 0.0f;
    float o0p_r1 = 0.0f, o1p_r1 = 0.0f, dg1 = 0.0f, cn1 = 0.0f;

    for (int jj = 0; jj < 16; ++jj) {
        const int j = (jj << 6) + sub;
        const float2 pj = pos2[j];                 // ds_read_b64, 2-way (free)
        const float dx0 = pj.x - pi0.x, dy0 = pj.y - pi0.y;
        const float dx1 = pj.x - pi1.x, dy1 = pj.y - pi1.y;
        unsigned long long m0 = __ballot(dx0 * dx0 + dy0 * dy0 < D2_PREFILTER);
        unsigned long long m1 = __ballot(dx1 * dx1 + dy1 * dy1 < D2_PREFILTER);

        while (m0) {
            const int src = __builtin_ctzll(m0);
            m0 &= (m0 - 1);
            const float bx = __shfl(dx0, src, 64);
            const float by = __shfl(dy0, src, 64);
            // exact fp32 path: bit-identical to numpy's boundary decisions
            const float d2 =
                __fadd_rn(__fadd_rn(__fmul_rn(bx, bx), __fmul_rn(by, by)), EPS);
            const float dist = __fsqrt_rn(d2);
            if (dist < RADIUS) {                   // uniform across wave
                const int bj = (jj << 6) + src;
                const float2 q0 = raw2[bj * 5 + 0];   // broadcast reads
                const float2 q1 = raw2[bj * 5 + 1];
                const float2 q2 = raw2[bj * 5 + 2];
                const float2 q3 = raw2[bj * 5 + 3];
                const float2 q4 = raw2[bj * 5 + 4];
                const float tgt = q2.x;
                float v = b1h;
                v = fmaf(q0.x, w1c[0], v);  v = fmaf(q0.y, w1c[1], v);
                v = fmaf(q1.x, w1c[2], v);  v = fmaf(q1.y, w1c[3], v);
                v = fmaf(q2.x, w1c[4], v);  v = fmaf(q2.y, w1c[5], v);
                v = fmaf(q3.x, w1c[6], v);  v = fmaf(q3.y, w1c[7], v);
                v = fmaf(q4.x, w1c[8], v);  v = fmaf(q4.y, w1c[9], v);
                v = fmaf(tgt,  w1t, v);
                v = fmaf(by,   w1y, v);
                v = fmaf(bx,   w1x, v);
                v = fmaf(dist, w1d, v);
                v = fmaxf(v, 0.0f);
                o0p_r0 = fmaf(v, w20, o0p_r0);
                o1p_r0 = fmaf(v, w21, o1p_r0);
                dg0 += 1.0f;                       // uniform on all lanes
                cn0 += (tgt > 0.5f) ? 1.0f : 0.0f;
            }
        }

        while (m1) {
            const int src = __builtin_ctzll(m1);
            m1 &= (m1 - 1);
            const float bx = __shfl(dx1, src, 64);
            const float by = __shfl(dy1, src, 64);
            const float d2 =
                __fadd_rn(__fadd_rn(__fmul_rn(bx, bx), __fmul_rn(by, by)), EPS);
            const float dist = __fsqrt_rn(d2);
            if (dist < RADIUS) {
                const int bj = (jj << 6) + src;
                const float2 q0 = raw2[bj * 5 + 0];
                const float2 q1 = raw2[bj * 5 + 1];
                const float2 q2 = raw2[bj * 5 + 2];
                const float2 q3 = raw2[bj * 5 + 3];
                const float2 q4 = raw2[bj * 5 + 4];
                const float tgt = q2.x;
                float v = b1h;
                v = fmaf(q0.x, w1c[0], v);  v = fmaf(q0.y, w1c[1], v);
                v = fmaf(q1.x, w1c[2], v);  v = fmaf(q1.y, w1c[3], v);
                v = fmaf(q2.x, w1c[4], v);  v = fmaf(q2.y, w1c[5], v);
                v = fmaf(q3.x, w1c[6], v);  v = fmaf(q3.y, w1c[7], v);
                v = fmaf(q4.x, w1c[8], v);  v = fmaf(q4.y, w1c[9], v);
                v = fmaf(tgt,  w1t, v);
                v = fmaf(by,   w1y, v);
                v = fmaf(bx,   w1x, v);
                v = fmaf(dist, w1d, v);
                v = fmaxf(v, 0.0f);
                o0p_r1 = fmaf(v, w20, o0p_r1);
                o1p_r1 = fmaf(v, w21, o1p_r1);
                dg1 += 1.0f;
                cn1 += (tgt > 0.5f) ? 1.0f : 0.0f;
            }
        }
    }

    // butterfly reduce the h-slice partials over 64 lanes (4 replicas -> x0.25)
#pragma unroll
    for (int mm = 1; mm < 64; mm <<= 1) {
        o0p_r0 += __shfl_xor(o0p_r0, mm, 64);
        o1p_r0 += __shfl_xor(o1p_r0, mm, 64);
        o0p_r1 += __shfl_xor(o0p_r1, mm, 64);
        o1p_r1 += __shfl_xor(o1p_r1, mm, 64);
    }

    // lanes 0 and 1 each finalize one row
    if (sub < 2) {
        const int iu = sub ? iu1 : iu0;
        const float2 pi = sub ? pi1 : pi0;
        const float o0p = (sub ? o0p_r1 : o0p_r0) * 0.25f;   // exact /4
        const float o1p = (sub ? o1p_r1 : o1p_r0) * 0.25f;
        const float deg = sub ? dg1 : dg0;
        const float cn  = sub ? cn1 : cn0;

        const float2 q1 = raw2[iu * 5 + 1];   // vel
        const float2 q2 = raw2[iu * 5 + 2];   // typ, c5
        const float2 q3 = raw2[iu * 5 + 3];   // c6, c7
        const float2 q4 = raw2[iu * 5 + 4];   // c8, c9

        const float typ_i = q2.x;
        const bool is_cell = typ_i > 0.5f;

        float o0 = deg * b2[0] + o0p;
        float o1 = deg * b2[1] + o1p;
        if (!is_cell) { o0 = 0.0f; o1 = 0.0f; }

        float nvx = q1.x, nvy = q1.y;
        float npx = pi.x, npy = pi.y;
        if (is_cell) {
            nvx = fminf(fmaxf(q1.x + o0 * ACCEL_SCALE, -MAX_VEL), MAX_VEL);
            nvy = fminf(fmaxf(q1.y + o1 * ACCEL_SCALE, -MAX_VEL), MAX_VEL);
            npx = fminf(fmaxf(pi.x + nvx, -MAX_POS), MAX_POS);
            npy = fminf(fmaxf(pi.y + nvy, -MAX_POS), MAX_POS);
        }

        const bool dead     = is_cell && (deg < 3.0f);
        const bool consumed = (!is_cell) && (cn >= 1.0f);
        const float keep = (dead || consumed) ? 0.0f : 1.0f;

        float2* __restrict__ op2 = (float2*)(out + ((size_t)b * NN + iu) * CC);
        op2[0] = make_float2(npx * keep, npy * keep);
        op2[1] = make_float2(nvx * keep, nvy * keep);
        op2[2] = make_float2(typ_i * keep, q2.y * keep);
        op2[3] = make_float2(q3.x * keep, q3.y * keep);
        op2[4] = make_float2(q4.x * keep, q4.y * keep);
    }
}

}  // namespace

extern "C" void kernel_launch(void* const* d_in, const int* in_sizes, int n_in,
                              void* d_out, int out_size, void* d_ws, size_t ws_size,
                              hipStream_t stream) {
    const float* x  = (const float*)d_in[0];
    const float* W1 = (const float*)d_in[1];
    const float* b1 = (const float*)d_in[2];
    const float* W2 = (const float*)d_in[3];
    const float* b2 = (const float*)d_in[4];
    float* out = (float*)d_out;

    gnca_one<<<dim3(BB * 64), dim3(512), 0, stream>>>(x, W1, b1, W2, b2, out);
}

// Round 10
// 11.998 us; speedup vs baseline: 3.3915x; 1.0317x over previous
//
#include <hip/hip_runtime.h>
#include <math.h>

namespace {

constexpr int BB = 8;
constexpr int NN = 1024;
constexpr int CC = 10;
constexpr float RADIUS = 0.04f;
constexpr float ACCEL_SCALE = 0.02f;
constexpr float MAX_VEL = 0.02f;
constexpr float MAX_POS = 1.0f;
constexpr float EPS = 1e-9f;
// superset prefilter: exact hit needs d2 < 0.0016; margin covers fma + ulps
constexpr float D2_PREFILTER = 0.0017f;

// ONE kernel, no workspace. grid = 512 blocks (8 batches x 64 chunks of 16
// rows), block = 512 threads = 8 waves. Wave w owns rows {2w, 2w+1}.
// Position reads are batched 8-at-a-time into registers (fully unrolled ->
// static indexing, one lgkmcnt wait per group of 8 instead of 16 serial
// LDS round-trips). Hits are ballot-compacted; hit body recomputes feat on
// the fly with per-lane h-slice weights (lane h = sub & 15; the 4 replica
// groups hold bit-identical partials, so a 4-step xor reduce within 16-lane
// groups gives the exact full h-sum with no x0.25 fold).
__global__ __launch_bounds__(512, 4) void gnca_one(
    const float* __restrict__ x,   // (B, N, 10)
    const float* __restrict__ W1,  // (14, 16) row-major
    const float* __restrict__ b1,  // (16,)
    const float* __restrict__ W2,  // (16, 7) row-major
    const float* __restrict__ b2,  // (7,)
    float* __restrict__ out)       // (B, N, 10)
{
    __shared__ alignas(16) float2 raw2[NN * 5];   // 40 KB: x[b] row-major
    __shared__ alignas(16) float2 pos2[NN];       // 8 KB

    const int tid = threadIdx.x;
    const int blk = blockIdx.x;          // 0..511
    const int b = blk >> 6;              // batch
    const int row0 = (blk & 63) * 16;    // 16 i-rows per block
    const int w   = tid >> 6;            // wave 0..7
    const int sub = tid & 63;            // 0..63
    const int hh  = sub & 15;            // this lane's h-slice

    // per-lane h-slice weights (vector loads, issued early, L2-resident)
    const float b1h = b1[hh];
    const float w1d = W1[hh];
    const float w1x = W1[16 + hh];
    const float w1y = W1[32 + hh];
    const float w1t = W1[48 + hh];
    float w1c[CC];
#pragma unroll
    for (int c = 0; c < CC; ++c) w1c[c] = W1[(4 + c) * 16 + hh];
    const float w20 = W2[hh * 7 + 0];
    const float w21 = W2[hh * 7 + 1];

    const float* __restrict__ xb = x + (size_t)b * NN * CC;

    // ---- Phase A: coalesced copy of x[b] (40 KB) into LDS ----
    {
        const float4* __restrict__ src = (const float4*)xb;   // 2560 float4
        float4* __restrict__ dst = (float4*)raw2;
#pragma unroll
        for (int k = 0; k < 5; ++k) dst[k * 512 + tid] = src[k * 512 + tid];
    }
    __syncthreads();

    // ---- Phase B: extract pos2 (thread t -> nodes 2t, 2t+1) ----
    {
        const float4* __restrict__ r4 = (const float4*)raw2;
        const float4 r0 = r4[tid * 5 + 0];   // node 2t   ch 0..3
        const float4 r2 = r4[tid * 5 + 2];   // node 2t+1 ch 0,1 in .z,.w
        ((float4*)pos2)[tid] = make_float4(r0.x, r0.y, r2.z, r2.w);
    }
    __syncthreads();

    const int iu0 = row0 + w * 2;
    const int iu1 = iu0 + 1;
    const float2 pi0 = pos2[iu0];   // wave-uniform -> broadcast
    const float2 pi1 = pos2[iu1];

    float o0p_r0 = 0.0f, o1p_r0 = 0.0f, dg0 = 0.0f, cn0 = 0.0f;
    float o0p_r1 = 0.0f, o1p_r1 = 0.0f, dg1 = 0.0f, cn1 = 0.0f;

#pragma unroll
    for (int g = 0; g < 2; ++g) {
        // batched position loads: 8 ds_read_b64 in flight, one wait
        float2 pjv[8];
#pragma unroll
        for (int q = 0; q < 8; ++q)
            pjv[q] = pos2[(((g << 3) + q) << 6) + sub];

#pragma unroll
        for (int q = 0; q < 8; ++q) {
            const int jj = (g << 3) + q;
            const float2 pj = pjv[q];
            const float dx0 = pj.x - pi0.x, dy0 = pj.y - pi0.y;
            const float dx1 = pj.x - pi1.x, dy1 = pj.y - pi1.y;
            unsigned long long m0 = __ballot(dx0 * dx0 + dy0 * dy0 < D2_PREFILTER);
            unsigned long long m1 = __ballot(dx1 * dx1 + dy1 * dy1 < D2_PREFILTER);

            while (m0) {
                const int src = __builtin_ctzll(m0);
                m0 &= (m0 - 1);
                const float bx = __shfl(dx0, src, 64);
                const float by = __shfl(dy0, src, 64);
                // exact fp32 path: bit-identical to numpy boundary decisions
                const float d2 =
                    __fadd_rn(__fadd_rn(__fmul_rn(bx, bx), __fmul_rn(by, by)), EPS);
                const float dist = __fsqrt_rn(d2);
                if (dist < RADIUS) {               // uniform across wave
                    const int bj = (jj << 6) + src;
                    const float2 q0 = raw2[bj * 5 + 0];   // broadcast reads
                    const float2 q1 = raw2[bj * 5 + 1];
                    const float2 q2 = raw2[bj * 5 + 2];
                    const float2 q3 = raw2[bj * 5 + 3];
                    const float2 q4 = raw2[bj * 5 + 4];
                    const float tgt = q2.x;
                    float v = b1h;
                    v = fmaf(q0.x, w1c[0], v);  v = fmaf(q0.y, w1c[1], v);
                    v = fmaf(q1.x, w1c[2], v);  v = fmaf(q1.y, w1c[3], v);
                    v = fmaf(q2.x, w1c[4], v);  v = fmaf(q2.y, w1c[5], v);
                    v = fmaf(q3.x, w1c[6], v);  v = fmaf(q3.y, w1c[7], v);
                    v = fmaf(q4.x, w1c[8], v);  v = fmaf(q4.y, w1c[9], v);
                    v = fmaf(tgt,  w1t, v);
                    v = fmaf(by,   w1y, v);
                    v = fmaf(bx,   w1x, v);
                    v = fmaf(dist, w1d, v);
                    v = fmaxf(v, 0.0f);
                    o0p_r0 = fmaf(v, w20, o0p_r0);
                    o1p_r0 = fmaf(v, w21, o1p_r0);
                    dg0 += 1.0f;                   // uniform on all lanes
                    cn0 += (tgt > 0.5f) ? 1.0f : 0.0f;
                }
            }

            while (m1) {
                const int src = __builtin_ctzll(m1);
                m1 &= (m1 - 1);
                const float bx = __shfl(dx1, src, 64);
                const float by = __shfl(dy1, src, 64);
                const float d2 =
                    __fadd_rn(__fadd_rn(__fmul_rn(bx, bx), __fmul_rn(by, by)), EPS);
                const float dist = __fsqrt_rn(d2);
                if (dist < RADIUS) {
                    const int bj = (jj << 6) + src;
                    const float2 q0 = raw2[bj * 5 + 0];
                    const float2 q1 = raw2[bj * 5 + 1];
                    const float2 q2 = raw2[bj * 5 + 2];
                    const float2 q3 = raw2[bj * 5 + 3];
                    const float2 q4 = raw2[bj * 5 + 4];
                    const float tgt = q2.x;
                    float v = b1h;
                    v = fmaf(q0.x, w1c[0], v);  v = fmaf(q0.y, w1c[1], v);
                    v = fmaf(q1.x, w1c[2], v);  v = fmaf(q1.y, w1c[3], v);
                    v = fmaf(q2.x, w1c[4], v);  v = fmaf(q2.y, w1c[5], v);
                    v = fmaf(q3.x, w1c[6], v);  v = fmaf(q3.y, w1c[7], v);
                    v = fmaf(q4.x, w1c[8], v);  v = fmaf(q4.y, w1c[9], v);
                    v = fmaf(tgt,  w1t, v);
                    v = fmaf(by,   w1y, v);
                    v = fmaf(bx,   w1x, v);
                    v = fmaf(dist, w1d, v);
                    v = fmaxf(v, 0.0f);
                    o0p_r1 = fmaf(v, w20, o0p_r1);
                    o1p_r1 = fmaf(v, w21, o1p_r1);
                    dg1 += 1.0f;
                    cn1 += (tgt > 0.5f) ? 1.0f : 0.0f;
                }
            }
        }
    }

    // 4-step reduce within 16-lane groups: replica groups are bit-identical,
    // so this equals the full 16-slice h-sum exactly (no x0.25 needed).
#pragma unroll
    for (int mm = 1; mm < 16; mm <<= 1) {
        o0p_r0 += __shfl_xor(o0p_r0, mm, 64);
        o1p_r0 += __shfl_xor(o1p_r0, mm, 64);
        o0p_r1 += __shfl_xor(o0p_r1, mm, 64);
        o1p_r1 += __shfl_xor(o1p_r1, mm, 64);
    }

    // lanes 0 and 1 each finalize one row
    if (sub < 2) {
        const int iu = sub ? iu1 : iu0;
        const float2 pi = sub ? pi1 : pi0;
        const float o0p = sub ? o0p_r1 : o0p_r0;
        const float o1p = sub ? o1p_r1 : o1p_r0;
        const float deg = sub ? dg1 : dg0;
        const float cn  = sub ? cn1 : cn0;

        const float2 q1 = raw2[iu * 5 + 1];   // vel
        const float2 q2 = raw2[iu * 5 + 2];   // typ, c5
        const float2 q3 = raw2[iu * 5 + 3];   // c6, c7
        const float2 q4 = raw2[iu * 5 + 4];   // c8, c9

        const float typ_i = q2.x;
        const bool is_cell = typ_i > 0.5f;

        float o0 = deg * b2[0] + o0p;
        float o1 = deg * b2[1] + o1p;
        if (!is_cell) { o0 = 0.0f; o1 = 0.0f; }

        float nvx = q1.x, nvy = q1.y;
        float npx = pi.x, npy = pi.y;
        if (is_cell) {
            nvx = fminf(fmaxf(q1.x + o0 * ACCEL_SCALE, -MAX_VEL), MAX_VEL);
            nvy = fminf(fmaxf(q1.y + o1 * ACCEL_SCALE, -MAX_VEL), MAX_VEL);
            npx = fminf(fmaxf(pi.x + nvx, -MAX_POS), MAX_POS);
            npy = fminf(fmaxf(pi.y + nvy, -MAX_POS), MAX_POS);
        }

        const bool dead     = is_cell && (deg < 3.0f);
        const bool consumed = (!is_cell) && (cn >= 1.0f);
        const float keep = (dead || consumed) ? 0.0f : 1.0f;

        float2* __restrict__ op2 = (float2*)(out + ((size_t)b * NN + iu) * CC);
        op2[0] = make_float2(npx * keep, npy * keep);
        op2[1] = make_float2(nvx * keep, nvy * keep);
        op2[2] = make_float2(typ_i * keep, q2.y * keep);
        op2[3] = make_float2(q3.x * keep, q3.y * keep);
        op2[4] = make_float2(q4.x * keep, q4.y * keep);
    }
}

}  // namespace

extern "C" void kernel_launch(void* const* d_in, const int* in_sizes, int n_in,
                              void* d_out, int out_size, void* d_ws, size_t ws_size,
                              hipStream_t stream) {
    const float* x  = (const float*)d_in[0];
    const float* W1 = (const float*)d_in[1];
    const float* b1 = (const float*)d_in[2];
    const float* W2 = (const float*)d_in[3];
    const float* b2 = (const float*)d_in[4];
    float* out = (float*)d_out;

    gnca_one<<<dim3(BB * 64), dim3(512), 0, stream>>>(x, W1, b1, W2, b2, out);
}

// Round 11
// 11.710 us; speedup vs baseline: 3.4747x; 1.0246x over previous
//
#include <hip/hip_runtime.h>
#include <math.h>

namespace {

constexpr int BB = 8;
constexpr int NN = 1024;
constexpr int CC = 10;
constexpr float RADIUS = 0.04f;
constexpr float ACCEL_SCALE = 0.02f;
constexpr float MAX_VEL = 0.02f;
constexpr float MAX_POS = 1.0f;
constexpr float EPS = 1e-9f;
// superset prefilter: exact hit needs d2 < 0.0016; margin covers fma + ulps
constexpr float D2_PREFILTER = 0.0017f;

// ONE kernel, no workspace. grid = 512 blocks (8 batches x 64 chunks of 16
// rows), block = 512 threads = 8 waves. Wave w owns rows {2w, 2w+1}.
// Hits are ballot-compacted. The hit body does NOT shfl-broadcast the rel
// vector (ds_bpermute, ~120cyc x2 serial); it recomputes it from the
// broadcast LDS read of the hit row's channels 0,1 (same bits, same ops ->
// bit-identical dist). Per-lane h-slice weights (lane h = sub & 15); the 4
// replica groups hold bit-identical partials, so a 4-step xor reduce within
// 16-lane groups yields the exact full h-sum.
__global__ __launch_bounds__(512, 4) void gnca_one(
    const float* __restrict__ x,   // (B, N, 10)
    const float* __restrict__ W1,  // (14, 16) row-major
    const float* __restrict__ b1,  // (16,)
    const float* __restrict__ W2,  // (16, 7) row-major
    const float* __restrict__ b2,  // (7,)
    float* __restrict__ out)       // (B, N, 10)
{
    __shared__ alignas(16) float2 raw2[NN * 5];   // 40 KB: x[b] row-major
    __shared__ alignas(16) float2 pos2[NN];       // 8 KB

    const int tid = threadIdx.x;
    const int blk = blockIdx.x;          // 0..511
    const int b = blk >> 6;              // batch
    const int row0 = (blk & 63) * 16;    // 16 i-rows per block
    const int w   = tid >> 6;            // wave 0..7
    const int sub = tid & 63;            // 0..63
    const int hh  = sub & 15;            // this lane's h-slice

    // per-lane h-slice weights (vector loads, issued early, L2-resident)
    const float b1h = b1[hh];
    const float w1d = W1[hh];
    const float w1x = W1[16 + hh];
    const float w1y = W1[32 + hh];
    const float w1t = W1[48 + hh];
    float w1c[CC];
#pragma unroll
    for (int c = 0; c < CC; ++c) w1c[c] = W1[(4 + c) * 16 + hh];
    const float w20 = W2[hh * 7 + 0];
    const float w21 = W2[hh * 7 + 1];

    const float* __restrict__ xb = x + (size_t)b * NN * CC;

    // ---- Phase A: coalesced copy of x[b] (40 KB) into LDS ----
    {
        const float4* __restrict__ src = (const float4*)xb;   // 2560 float4
        float4* __restrict__ dst = (float4*)raw2;
#pragma unroll
        for (int k = 0; k < 5; ++k) dst[k * 512 + tid] = src[k * 512 + tid];
    }
    __syncthreads();

    // ---- Phase B: extract pos2 (thread t -> nodes 2t, 2t+1) ----
    {
        const float4* __restrict__ r4 = (const float4*)raw2;
        const float4 r0 = r4[tid * 5 + 0];   // node 2t   ch 0..3
        const float4 r2 = r4[tid * 5 + 2];   // node 2t+1 ch 0,1 in .z,.w
        ((float4*)pos2)[tid] = make_float4(r0.x, r0.y, r2.z, r2.w);
    }
    __syncthreads();

    const int iu0 = row0 + w * 2;
    const int iu1 = iu0 + 1;
    const float2 pi0 = pos2[iu0];   // wave-uniform -> broadcast
    const float2 pi1 = pos2[iu1];

    float o0p_r0 = 0.0f, o1p_r0 = 0.0f, dg0 = 0.0f, cn0 = 0.0f;
    float o0p_r1 = 0.0f, o1p_r1 = 0.0f, dg1 = 0.0f, cn1 = 0.0f;

#pragma unroll
    for (int g = 0; g < 2; ++g) {
        // batched position loads: 8 ds_read_b64 in flight, one wait
        float2 pjv[8];
#pragma unroll
        for (int q = 0; q < 8; ++q)
            pjv[q] = pos2[(((g << 3) + q) << 6) + sub];

#pragma unroll
        for (int q = 0; q < 8; ++q) {
            const int jj = (g << 3) + q;
            const float2 pj = pjv[q];
            const float dx0 = pj.x - pi0.x, dy0 = pj.y - pi0.y;
            const float dx1 = pj.x - pi1.x, dy1 = pj.y - pi1.y;
            unsigned long long m0 = __ballot(dx0 * dx0 + dy0 * dy0 < D2_PREFILTER);
            unsigned long long m1 = __ballot(dx1 * dx1 + dy1 * dy1 < D2_PREFILTER);

            while (m0) {
                const int src = __builtin_ctzll(m0);
                m0 &= (m0 - 1);
                const int bj = (jj << 6) + src;          // wave-uniform
                const float2 q0 = raw2[bj * 5 + 0];      // broadcast reads,
                const float2 q1 = raw2[bj * 5 + 1];      // independent ->
                const float2 q2 = raw2[bj * 5 + 2];      // one lgkm wait
                const float2 q3 = raw2[bj * 5 + 3];
                const float2 q4 = raw2[bj * 5 + 4];
                // recompute rel in-register: same bits as source lane's dx,dy
                const float bx = q0.x - pi0.x;
                const float by = q0.y - pi0.y;
                // exact fp32 path: bit-identical to numpy boundary decisions
                const float d2 =
                    __fadd_rn(__fadd_rn(__fmul_rn(bx, bx), __fmul_rn(by, by)), EPS);
                const float dist = __fsqrt_rn(d2);
                if (dist < RADIUS) {                     // uniform across wave
                    const float tgt = q2.x;
                    float v = b1h;
                    v = fmaf(q0.x, w1c[0], v);  v = fmaf(q0.y, w1c[1], v);
                    v = fmaf(q1.x, w1c[2], v);  v = fmaf(q1.y, w1c[3], v);
                    v = fmaf(q2.x, w1c[4], v);  v = fmaf(q2.y, w1c[5], v);
                    v = fmaf(q3.x, w1c[6], v);  v = fmaf(q3.y, w1c[7], v);
                    v = fmaf(q4.x, w1c[8], v);  v = fmaf(q4.y, w1c[9], v);
                    v = fmaf(tgt,  w1t, v);
                    v = fmaf(by,   w1y, v);
                    v = fmaf(bx,   w1x, v);
                    v = fmaf(dist, w1d, v);
                    v = fmaxf(v, 0.0f);
                    o0p_r0 = fmaf(v, w20, o0p_r0);
                    o1p_r0 = fmaf(v, w21, o1p_r0);
                    dg0 += 1.0f;                         // uniform on all lanes
                    cn0 += (tgt > 0.5f) ? 1.0f : 0.0f;
                }
            }

            while (m1) {
                const int src = __builtin_ctzll(m1);
                m1 &= (m1 - 1);
                const int bj = (jj << 6) + src;
                const float2 q0 = raw2[bj * 5 + 0];
                const float2 q1 = raw2[bj * 5 + 1];
                const float2 q2 = raw2[bj * 5 + 2];
                const float2 q3 = raw2[bj * 5 + 3];
                const float2 q4 = raw2[bj * 5 + 4];
                const float bx = q0.x - pi1.x;
                const float by = q0.y - pi1.y;
                const float d2 =
                    __fadd_rn(__fadd_rn(__fmul_rn(bx, bx), __fmul_rn(by, by)), EPS);
                const float dist = __fsqrt_rn(d2);
                if (dist < RADIUS) {
                    const float tgt = q2.x;
                    float v = b1h;
                    v = fmaf(q0.x, w1c[0], v);  v = fmaf(q0.y, w1c[1], v);
                    v = fmaf(q1.x, w1c[2], v);  v = fmaf(q1.y, w1c[3], v);
                    v = fmaf(q2.x, w1c[4], v);  v = fmaf(q2.y, w1c[5], v);
                    v = fmaf(q3.x, w1c[6], v);  v = fmaf(q3.y, w1c[7], v);
                    v = fmaf(q4.x, w1c[8], v);  v = fmaf(q4.y, w1c[9], v);
                    v = fmaf(tgt,  w1t, v);
                    v = fmaf(by,   w1y, v);
                    v = fmaf(bx,   w1x, v);
                    v = fmaf(dist, w1d, v);
                    v = fmaxf(v, 0.0f);
                    o0p_r1 = fmaf(v, w20, o0p_r1);
                    o1p_r1 = fmaf(v, w21, o1p_r1);
                    dg1 += 1.0f;
                    cn1 += (tgt > 0.5f) ? 1.0f : 0.0f;
                }
            }
        }
    }

    // 4-step reduce within 16-lane groups: replica groups are bit-identical,
    // so this equals the full 16-slice h-sum exactly (no x0.25 needed).
#pragma unroll
    for (int mm = 1; mm < 16; mm <<= 1) {
        o0p_r0 += __shfl_xor(o0p_r0, mm, 64);
        o1p_r0 += __shfl_xor(o1p_r0, mm, 64);
        o0p_r1 += __shfl_xor(o0p_r1, mm, 64);
        o1p_r1 += __shfl_xor(o1p_r1, mm, 64);
    }

    // lanes 0 and 1 each finalize one row
    if (sub < 2) {
        const int iu = sub ? iu1 : iu0;
        const float2 pi = sub ? pi1 : pi0;
        const float o0p = sub ? o0p_r1 : o0p_r0;
        const float o1p = sub ? o1p_r1 : o1p_r0;
        const float deg = sub ? dg1 : dg0;
        const float cn  = sub ? cn1 : cn0;

        const float2 q1 = raw2[iu * 5 + 1];   // vel
        const float2 q2 = raw2[iu * 5 + 2];   // typ, c5
        const float2 q3 = raw2[iu * 5 + 3];   // c6, c7
        const float2 q4 = raw2[iu * 5 + 4];   // c8, c9

        const float typ_i = q2.x;
        const bool is_cell = typ_i > 0.5f;

        float o0 = deg * b2[0] + o0p;
        float o1 = deg * b2[1] + o1p;
        if (!is_cell) { o0 = 0.0f; o1 = 0.0f; }

        float nvx = q1.x, nvy = q1.y;
        float npx = pi.x, npy = pi.y;
        if (is_cell) {
            nvx = fminf(fmaxf(q1.x + o0 * ACCEL_SCALE, -MAX_VEL), MAX_VEL);
            nvy = fminf(fmaxf(q1.y + o1 * ACCEL_SCALE, -MAX_VEL), MAX_VEL);
            npx = fminf(fmaxf(pi.x + nvx, -MAX_POS), MAX_POS);
            npy = fminf(fmaxf(pi.y + nvy, -MAX_POS), MAX_POS);
        }

        const bool dead     = is_cell && (deg < 3.0f);
        const bool consumed = (!is_cell) && (cn >= 1.0f);
        const float keep = (dead || consumed) ? 0.0f : 1.0f;

        float2* __restrict__ op2 = (float2*)(out + ((size_t)b * NN + iu) * CC);
        op2[0] = make_float2(npx * keep, npy * keep);
        op2[1] = make_float2(nvx * keep, nvy * keep);
        op2[2] = make_float2(typ_i * keep, q2.y * keep);
        op2[3] = make_float2(q3.x * keep, q3.y * keep);
        op2[4] = make_float2(q4.x * keep, q4.y * keep);
    }
}

}  // namespace

extern "C" void kernel_launch(void* const* d_in, const int* in_sizes, int n_in,
                              void* d_out, int out_size, void* d_ws, size_t ws_size,
                              hipStream_t stream) {
    const float* x  = (const float*)d_in[0];
    const float* W1 = (const float*)d_in[1];
    const float* b1 = (const float*)d_in[2];
    const float* W2 = (const float*)d_in[3];
    const float* b2 = (const float*)d_in[4];
    float* out = (float*)d_out;

    gnca_one<<<dim3(BB * 64), dim3(512), 0, stream>>>(x, W1, b1, W2, b2, out);
}